// Round 10
// baseline (168.478 us; speedup 1.0000x reference)
//
#include <hip/hip_runtime.h>
#include <hip/hip_fp8.h>

#define VOCAB 100000
#define DIM 128
#define BATCH 65536
#define N_NEG 10

#define BLOCKS (BATCH / 32)   // 8 lanes/elem, 8 elem/wave, 4 waves/block
#define QSCALE 256.0f
#define QINV   (1.0f / (256.0f * 256.0f))
#define NGRP   (VOCAB * DIM / 16)   // 16-float groups per table = 800000

typedef unsigned int uiv4 __attribute__((ext_vector_type(4)));

// ---------- fp8 helpers ----------
__device__ __forceinline__ unsigned int pack4_fp8(float a, float b, float c, float d) {
    unsigned int r =  (unsigned int)__hip_fp8_e4m3(a).__x;
    r |= (unsigned int)__hip_fp8_e4m3(b).__x << 8;
    r |= (unsigned int)__hip_fp8_e4m3(c).__x << 16;
    r |= (unsigned int)__hip_fp8_e4m3(d).__x << 24;
    return r;
}

#if __has_builtin(__builtin_amdgcn_cvt_pk_f32_fp8)
typedef float v2f __attribute__((ext_vector_type(2)));
__device__ __forceinline__ void unpack4_fp8(float* u, unsigned int x) {
    v2f lo = __builtin_amdgcn_cvt_pk_f32_fp8(x, false);
    v2f hi = __builtin_amdgcn_cvt_pk_f32_fp8(x, true);
    u[0] = lo.x; u[1] = lo.y; u[2] = hi.x; u[3] = hi.y;
}
#else
__device__ __forceinline__ float fp8_to_f(unsigned int b) {
    __hip_fp8_e4m3 t; t.__x = (__hip_fp8_storage_t)b; return (float)t;
}
__device__ __forceinline__ void unpack4_fp8(float* u, unsigned int x) {
    u[0] = fp8_to_f(x & 0xffu);        u[1] = fp8_to_f((x >> 8) & 0xffu);
    u[2] = fp8_to_f((x >> 16) & 0xffu); u[3] = fp8_to_f(x >> 24);
}
#endif

__device__ __forceinline__ float dot16_fp8(uint4 w, const float* uf) {
    float t[16];
    unpack4_fp8(t + 0,  w.x);
    unpack4_fp8(t + 4,  w.y);
    unpack4_fp8(t + 8,  w.z);
    unpack4_fp8(t + 12, w.w);
    float s = 0.0f;
    #pragma unroll
    for (int k = 0; k < 16; ++k) s += uf[k] * t[k];
    return s;
}

// softplus(x)/ln2 = max(y,0) + log2(1+2^-|y|), y = x*log2e  (native exp2/log2)
__device__ __forceinline__ float softplus_log2(float x) {
    const float y = x * 1.44269504f;
    const float t = __builtin_amdgcn_exp2f(-fabsf(y));
    return fmaxf(y, 0.0f) + __builtin_amdgcn_logf(1.0f + t);
}

__global__ void zero_out_kernel(float* out) { out[0] = 0.0f; }

// ---------- fused quantize of BOTH tables (one launch), zero-out folded in ----------
__global__ __launch_bounds__(256) void quantize_both_kernel(
    const float4* __restrict__ u_in, const float4* __restrict__ v_in,
    uiv4* __restrict__ u8, uiv4* __restrict__ v8, float* __restrict__ loss_out) {
    const int i = blockIdx.x * 256 + threadIdx.x;   // one 16-float group
    if (i == 0) loss_out[0] = 0.0f;
    const float4* __restrict__ src; uiv4* __restrict__ dst; int j;
    if (i < NGRP) { src = u_in; dst = u8; j = i; }
    else          { src = v_in; dst = v8; j = i - NGRP; }
    const float4 a = src[j * 4 + 0];
    const float4 b = src[j * 4 + 1];
    const float4 c = src[j * 4 + 2];
    const float4 d = src[j * 4 + 3];
    uiv4 r;
    r.x = pack4_fp8(a.x * QSCALE, a.y * QSCALE, a.z * QSCALE, a.w * QSCALE);
    r.y = pack4_fp8(b.x * QSCALE, b.y * QSCALE, b.z * QSCALE, b.w * QSCALE);
    r.z = pack4_fp8(c.x * QSCALE, c.y * QSCALE, c.z * QSCALE, c.w * QSCALE);
    r.w = pack4_fp8(d.x * QSCALE, d.y * QSCALE, d.z * QSCALE, d.w * QSCALE);
    // nontemporal: these lines are consumed by gather waves on OTHER XCDs;
    // push them toward L3 instead of leaving dirty home-L2 lines.
    __builtin_nontemporal_store(r, dst + j);
}

// ---------- all-fp8 gather: u row = 1 line (read once), v row = 1 line (read 11x) ----------
__global__ __launch_bounds__(256) void skipgram_loss_fp8_kernel(
    const int* __restrict__ pos_u,
    const int* __restrict__ pos_v,
    const int* __restrict__ neg_v,
    const uint4* __restrict__ u8,    // VOCAB x 8 uint4 (128 B/row)
    const uint4* __restrict__ v8,
    float* __restrict__ out)
{
    const int tid  = threadIdx.x;
    const int lane = tid & 63;
    const int wave = tid >> 6;
    const int sub  = lane & 7;       // 16 B slice within the 128-B row
    const int grp  = lane >> 3;

    const int b = (blockIdx.x * 4 + wave) * 8 + grp;

    const int iu = pos_u[b];
    const int iv = pos_v[b];

    const uint4 uq = u8[iu * 8 + sub];
    float uf[16];
    unpack4_fp8(uf + 0,  uq.x);
    unpack4_fp8(uf + 4,  uq.y);
    unpack4_fp8(uf + 8,  uq.z);
    unpack4_fp8(uf + 12, uq.w);

    float acc[N_NEG + 1];
    acc[0] = dot16_fp8(v8[iv * 8 + sub], uf);
    #pragma unroll
    for (int n = 0; n < N_NEG; ++n) {
        const int idx = neg_v[b * N_NEG + n];
        acc[n + 1] = dot16_fp8(v8[idx * 8 + sub], uf);
    }

    #pragma unroll
    for (int m = 1; m < 8; m <<= 1) {
        #pragma unroll
        for (int j = 0; j <= N_NEG; ++j) acc[j] += __shfl_xor(acc[j], m, 64);
    }

    float s = fminf(fmaxf(acc[0] * QINV, -10.0f), 10.0f);
    float loss2 = softplus_log2(-s);
    #pragma unroll
    for (int n = 0; n < N_NEG; ++n)
        loss2 -= softplus_log2(acc[n + 1] * QINV);
    float loss = loss2 * 0.69314718f;

    #pragma unroll
    for (int m = 8; m < 64; m <<= 1) loss += __shfl_xor(loss, m, 64);

    __shared__ float smem[4];
    if (lane == 0) smem[wave] = loss;
    __syncthreads();
    if (tid == 0)
        atomicAdd(out, (smem[0] + smem[1] + smem[2] + smem[3]) * (1.0f / (float)BATCH));
}

// ---------- fp32 fallback if ws is too small ----------
__device__ __forceinline__ float dot4(float4 a, float4 b) {
    return a.x * b.x + a.y * b.y + a.z * b.z + a.w * b.w;
}

__global__ __launch_bounds__(256) void skipgram_loss_fp32_kernel(
    const int* __restrict__ pos_u,
    const int* __restrict__ pos_v,
    const int* __restrict__ neg_v,
    const float4* __restrict__ u_weight,
    const float4* __restrict__ v_weight,
    float* __restrict__ out)
{
    const int tid  = threadIdx.x;
    const int lane = tid & 63;
    const int wave = tid >> 6;
    const int sub  = lane & 7;
    const int grp  = lane >> 3;

    const int b = (blockIdx.x * 4 + wave) * 8 + grp;

    const int iu = pos_u[b];
    const int iv = pos_v[b];

    const float4* __restrict__ urow = u_weight + iu * 32;
    float4 u0 = urow[0 * 8 + sub];
    float4 u1 = urow[1 * 8 + sub];
    float4 u2 = urow[2 * 8 + sub];
    float4 u3 = urow[3 * 8 + sub];

    const float4* __restrict__ vrow = v_weight + iv * 32;
    float p = dot4(u0, vrow[0 * 8 + sub]) + dot4(u1, vrow[1 * 8 + sub])
            + dot4(u2, vrow[2 * 8 + sub]) + dot4(u3, vrow[3 * 8 + sub]);

    float nd[N_NEG];
    #pragma unroll
    for (int n = 0; n < N_NEG; ++n) {
        const int idx = neg_v[b * N_NEG + n];
        const float4* __restrict__ wrow = v_weight + idx * 32;
        nd[n] = dot4(u0, wrow[0 * 8 + sub]) + dot4(u1, wrow[1 * 8 + sub])
              + dot4(u2, wrow[2 * 8 + sub]) + dot4(u3, wrow[3 * 8 + sub]);
    }

    #pragma unroll
    for (int m = 1; m < 8; m <<= 1) {
        p += __shfl_xor(p, m, 64);
        #pragma unroll
        for (int n = 0; n < N_NEG; ++n) nd[n] += __shfl_xor(nd[n], m, 64);
    }

    float s = fminf(fmaxf(p, -10.0f), 10.0f);
    float loss2 = softplus_log2(-s);
    #pragma unroll
    for (int n = 0; n < N_NEG; ++n) loss2 -= softplus_log2(nd[n]);
    float loss = loss2 * 0.69314718f;

    #pragma unroll
    for (int m = 8; m < 64; m <<= 1) loss += __shfl_xor(loss, m, 64);

    __shared__ float smem[4];
    if (lane == 0) smem[wave] = loss;
    __syncthreads();
    if (tid == 0)
        atomicAdd(out, (smem[0] + smem[1] + smem[2] + smem[3]) * (1.0f / (float)BATCH));
}

extern "C" void kernel_launch(void* const* d_in, const int* in_sizes, int n_in,
                              void* d_out, int out_size, void* d_ws, size_t ws_size,
                              hipStream_t stream) {
    const int*    pos_u    = (const int*)d_in[0];
    const int*    pos_v    = (const int*)d_in[1];
    const int*    neg_v    = (const int*)d_in[2];
    const float4* u_weight = (const float4*)d_in[3];
    const float4* v_weight = (const float4*)d_in[4];
    float* out = (float*)d_out;

    const size_t table_bytes = (size_t)VOCAB * DIM;        // 12.8 MB per fp8 table
    if (ws_size >= 2 * table_bytes) {
        uiv4* u8 = (uiv4*)d_ws;
        uiv4* v8 = (uiv4*)((char*)d_ws + table_bytes);
        const int qblocks = 2 * NGRP / 256;                // 6250
        quantize_both_kernel<<<qblocks, 256, 0, stream>>>(u_weight, v_weight, u8, v8, out);
        skipgram_loss_fp8_kernel<<<BLOCKS, 256, 0, stream>>>(
            pos_u, pos_v, neg_v, (const uint4*)u8, (const uint4*)v8, out);
    } else {
        zero_out_kernel<<<1, 1, 0, stream>>>(out);
        skipgram_loss_fp32_kernel<<<BLOCKS, 256, 0, stream>>>(
            pos_u, pos_v, neg_v, u_weight, v_weight, out);
    }
}

// Round 11
// 139.448 us; speedup vs baseline: 1.2082x; 1.2082x over previous
//
#include <hip/hip_runtime.h>
#include <hip/hip_fp8.h>

#define VOCAB 100000
#define DIM 128
#define BATCH 65536
#define N_NEG 10

// 8 lanes/group, 2 elements/group, 8 groups/wave, 4 waves/block => 64 elems/block
#define BLOCKS (BATCH / 64)   // 1024
#define QSCALE 256.0f
#define QINV   (1.0f / 256.0f)

// ---------- fp8 helpers ----------
__device__ __forceinline__ unsigned int pack4_fp8(float a, float b, float c, float d) {
    unsigned int r =  (unsigned int)__hip_fp8_e4m3(a).__x;
    r |= (unsigned int)__hip_fp8_e4m3(b).__x << 8;
    r |= (unsigned int)__hip_fp8_e4m3(c).__x << 16;
    r |= (unsigned int)__hip_fp8_e4m3(d).__x << 24;
    return r;
}

#if __has_builtin(__builtin_amdgcn_cvt_pk_f32_fp8)
typedef float v2f __attribute__((ext_vector_type(2)));
__device__ __forceinline__ void fma4_fp8(float& s, unsigned int x, const float* u) {
    v2f lo = __builtin_amdgcn_cvt_pk_f32_fp8(x, false);
    v2f hi = __builtin_amdgcn_cvt_pk_f32_fp8(x, true);
    s += u[0] * lo.x + u[1] * lo.y + u[2] * hi.x + u[3] * hi.y;
}
#else
__device__ __forceinline__ float fp8_to_f(unsigned int b) {
    __hip_fp8_e4m3 t; t.__x = (__hip_fp8_storage_t)b; return (float)t;
}
__device__ __forceinline__ void fma4_fp8(float& s, unsigned int x, const float* u) {
    s += u[0] * fp8_to_f(x & 0xffu) + u[1] * fp8_to_f((x >> 8) & 0xffu)
       + u[2] * fp8_to_f((x >> 16) & 0xffu) + u[3] * fp8_to_f(x >> 24);
}
#endif

__device__ __forceinline__ float dot16_fp8(uint4 w, const float* uf) {
    float s = 0.0f;
    fma4_fp8(s, w.x, uf + 0);
    fma4_fp8(s, w.y, uf + 4);
    fma4_fp8(s, w.z, uf + 8);
    fma4_fp8(s, w.w, uf + 12);
    return s;
}

// softplus(x)/ln2 = max(y,0) + log2(1+2^-|y|), y = x*log2e  (native exp2/log2)
__device__ __forceinline__ float softplus_log2(float x) {
    const float y = x * 1.44269504f;
    const float t = __builtin_amdgcn_exp2f(-fabsf(y));
    return fmaxf(y, 0.0f) + __builtin_amdgcn_logf(1.0f + t);
}

__global__ void zero_out_kernel(float* out) { out[0] = 0.0f; }

// ---------- quantize v-table only (zero-out folded in); regular stores keep lines cache-warm ----------
__global__ __launch_bounds__(256) void quantize_v_kernel(
    const float4* __restrict__ in, uint4* __restrict__ out, float* __restrict__ loss_out) {
    const int i = blockIdx.x * 256 + threadIdx.x;   // one 16-float group
    if (i == 0) loss_out[0] = 0.0f;
    const float4 a = in[i * 4 + 0];
    const float4 b = in[i * 4 + 1];
    const float4 c = in[i * 4 + 2];
    const float4 d = in[i * 4 + 3];
    uint4 r;
    r.x = pack4_fp8(a.x * QSCALE, a.y * QSCALE, a.z * QSCALE, a.w * QSCALE);
    r.y = pack4_fp8(b.x * QSCALE, b.y * QSCALE, b.z * QSCALE, b.w * QSCALE);
    r.z = pack4_fp8(c.x * QSCALE, c.y * QSCALE, c.z * QSCALE, c.w * QSCALE);
    r.w = pack4_fp8(d.x * QSCALE, d.y * QSCALE, d.z * QSCALE, d.w * QSCALE);
    out[i] = r;
}

// ---------- gather: 2 elements per 8-lane group (24 row-loads in flight per wave) ----------
__global__ __launch_bounds__(256, 4) void skipgram_loss_fp8_kernel(
    const int* __restrict__ pos_u,
    const int* __restrict__ pos_v,
    const int* __restrict__ neg_v,
    const float4* __restrict__ u_weight,   // VOCAB x 32 float4 (fp32)
    const uint4* __restrict__ v8,          // VOCAB x 8 uint4 (fp8, 128 B/row)
    float* __restrict__ out)
{
    const int tid  = threadIdx.x;
    const int lane = tid & 63;
    const int wave = tid >> 6;
    const int sub  = lane & 7;       // 16 B slice within the 128-B fp8 row
    const int grp  = lane >> 3;

    const int gg = (blockIdx.x * 4 + wave) * 8 + grp;  // global group id
    const int b0 = gg * 2;
    const int b1 = b0 + 1;

    const int iu0 = pos_u[b0], iu1 = pos_u[b1];
    const int iv0 = pos_v[b0], iv1 = pos_v[b1];

    // u rows in fp32: this lane's 16 floats per element
    const float4* __restrict__ urow0 = u_weight + iu0 * 32 + sub * 4;
    const float4* __restrict__ urow1 = u_weight + iu1 * 32 + sub * 4;
    float uf0[16], uf1[16];
    #pragma unroll
    for (int q = 0; q < 4; ++q) {
        const float4 t0 = urow0[q];
        uf0[q * 4 + 0] = t0.x; uf0[q * 4 + 1] = t0.y;
        uf0[q * 4 + 2] = t0.z; uf0[q * 4 + 3] = t0.w;
        const float4 t1 = urow1[q];
        uf1[q * 4 + 0] = t1.x; uf1[q * 4 + 1] = t1.y;
        uf1[q * 4 + 2] = t1.z; uf1[q * 4 + 3] = t1.w;
    }

    float a0[N_NEG + 1], a1[N_NEG + 1];
    a0[0] = dot16_fp8(v8[iv0 * 8 + sub], uf0);
    a1[0] = dot16_fp8(v8[iv1 * 8 + sub], uf1);
    #pragma unroll
    for (int n = 0; n < N_NEG; ++n) {
        const int i0 = neg_v[b0 * N_NEG + n];
        const int i1 = neg_v[b1 * N_NEG + n];
        a0[n + 1] = dot16_fp8(v8[i0 * 8 + sub], uf0);
        a1[n + 1] = dot16_fp8(v8[i1 * 8 + sub], uf1);
    }

    #pragma unroll
    for (int m = 1; m < 8; m <<= 1) {
        #pragma unroll
        for (int j = 0; j <= N_NEG; ++j) {
            a0[j] += __shfl_xor(a0[j], m, 64);
            a1[j] += __shfl_xor(a1[j], m, 64);
        }
    }

    float s0 = fminf(fmaxf(a0[0] * QINV, -10.0f), 10.0f);
    float s1 = fminf(fmaxf(a1[0] * QINV, -10.0f), 10.0f);
    float loss2 = softplus_log2(-s0) + softplus_log2(-s1);
    #pragma unroll
    for (int n = 0; n < N_NEG; ++n)
        loss2 -= softplus_log2(a0[n + 1] * QINV) + softplus_log2(a1[n + 1] * QINV);
    float loss = loss2 * 0.69314718f;   // loss(b0) + loss(b1), uniform in group

    // Butterfly over masks 8,16,32 sums the 8 distinct group values once each.
    #pragma unroll
    for (int m = 8; m < 64; m <<= 1) loss += __shfl_xor(loss, m, 64);

    __shared__ float smem[4];
    if (lane == 0) smem[wave] = loss;
    __syncthreads();
    if (tid == 0)
        atomicAdd(out, (smem[0] + smem[1] + smem[2] + smem[3]) * (1.0f / (float)BATCH));
}

// ---------- fp32 fallback if ws is too small ----------
__device__ __forceinline__ float dot4(float4 a, float4 b) {
    return a.x * b.x + a.y * b.y + a.z * b.z + a.w * b.w;
}

__global__ __launch_bounds__(256) void skipgram_loss_fp32_kernel(
    const int* __restrict__ pos_u,
    const int* __restrict__ pos_v,
    const int* __restrict__ neg_v,
    const float4* __restrict__ u_weight,
    const float4* __restrict__ v_weight,
    float* __restrict__ out)
{
    const int tid  = threadIdx.x;
    const int lane = tid & 63;
    const int wave = tid >> 6;
    const int sub  = lane & 7;
    const int grp  = lane >> 3;

    const int b = ((blockIdx.x * 4 + wave) * 8 + grp);

    const int iu = pos_u[b];
    const int iv = pos_v[b];

    const float4* __restrict__ urow = u_weight + iu * 32;
    float4 u0 = urow[0 * 8 + sub];
    float4 u1 = urow[1 * 8 + sub];
    float4 u2 = urow[2 * 8 + sub];
    float4 u3 = urow[3 * 8 + sub];

    const float4* __restrict__ vrow = v_weight + iv * 32;
    float p = dot4(u0, vrow[0 * 8 + sub]) + dot4(u1, vrow[1 * 8 + sub])
            + dot4(u2, vrow[2 * 8 + sub]) + dot4(u3, vrow[3 * 8 + sub]);

    float nd[N_NEG];
    #pragma unroll
    for (int n = 0; n < N_NEG; ++n) {
        const int idx = neg_v[b * N_NEG + n];
        const float4* __restrict__ wrow = v_weight + idx * 32;
        nd[n] = dot4(u0, wrow[0 * 8 + sub]) + dot4(u1, wrow[1 * 8 + sub])
              + dot4(u2, wrow[2 * 8 + sub]) + dot4(u3, wrow[3 * 8 + sub]);
    }

    #pragma unroll
    for (int m = 1; m < 8; m <<= 1) {
        p += __shfl_xor(p, m, 64);
        #pragma unroll
        for (int n = 0; n < N_NEG; ++n) nd[n] += __shfl_xor(nd[n], m, 64);
    }

    float s = fminf(fmaxf(p, -10.0f), 10.0f);
    float loss2 = softplus_log2(-s);
    #pragma unroll
    for (int n = 0; n < N_NEG; ++n) loss2 -= softplus_log2(nd[n]);
    float loss = loss2 * 0.69314718f;

    #pragma unroll
    for (int m = 8; m < 64; m <<= 1) loss += __shfl_xor(loss, m, 64);

    __shared__ float smem[4];
    if (lane == 0) smem[wave] = loss;
    __syncthreads();
    if (tid == 0)
        atomicAdd(out, (smem[0] + smem[1] + smem[2] + smem[3]) * (1.0f / (float)BATCH));
}

extern "C" void kernel_launch(void* const* d_in, const int* in_sizes, int n_in,
                              void* d_out, int out_size, void* d_ws, size_t ws_size,
                              hipStream_t stream) {
    const int*    pos_u    = (const int*)d_in[0];
    const int*    pos_v    = (const int*)d_in[1];
    const int*    neg_v    = (const int*)d_in[2];
    const float4* u_weight = (const float4*)d_in[3];
    const float4* v_weight = (const float4*)d_in[4];
    float* out = (float*)d_out;

    const size_t table_bytes = (size_t)VOCAB * DIM;        // 12.8 MB fp8
    if (ws_size >= table_bytes) {
        uint4* v8 = (uint4*)d_ws;
        const int qblocks = (VOCAB * DIM / 16) / 256;      // 3125
        quantize_v_kernel<<<qblocks, 256, 0, stream>>>(v_weight, v8, out);
        skipgram_loss_fp8_kernel<<<BLOCKS, 256, 0, stream>>>(
            pos_u, pos_v, neg_v, u_weight, v8, out);
    } else {
        zero_out_kernel<<<1, 1, 0, stream>>>(out);
        skipgram_loss_fp32_kernel<<<BATCH / 32, 256, 0, stream>>>(
            pos_u, pos_v, neg_v, u_weight, v_weight, out);
    }
}